// Round 1
// baseline (15.676 us; speedup 1.0000x reference)
//
#include <hip/hip_runtime.h>

// Reference collapses:
//   encode: f0=0, lr0=1 -> grad0=-x, f1=x; grads for t>=1 are 0.
//           spike0 = 0.5*(1-x), spike_t = 0.5 (t>=1)
//   decode: grad0 = 2*spike0-1 = (1-x)-1, y = -grad0; grads for t>=1 are 0.
//   => out = -((1-x)-1), bit-exact with the fp32 reference (x*0.5/2.0 exact).
__global__ __launch_bounds__(256) void codec_kernel(const float4* __restrict__ x,
                                                    float4* __restrict__ out,
                                                    int n4) {
    int i = blockIdx.x * blockDim.x + threadIdx.x;
    if (i < n4) {
        float4 v = x[i];
        float4 r;
        r.x = -((1.0f - v.x) - 1.0f);
        r.y = -((1.0f - v.y) - 1.0f);
        r.z = -((1.0f - v.z) - 1.0f);
        r.w = -((1.0f - v.w) - 1.0f);
        out[i] = r;
    }
}

extern "C" void kernel_launch(void* const* d_in, const int* in_sizes, int n_in,
                              void* d_out, int out_size, void* d_ws, size_t ws_size,
                              hipStream_t stream) {
    const float4* x = (const float4*)d_in[0];
    float4* out = (float4*)d_out;
    int n = in_sizes[0];            // 8388608, divisible by 4
    int n4 = n / 4;                 // 2097152
    int block = 256;
    int grid = (n4 + block - 1) / block;  // 8192
    codec_kernel<<<grid, block, 0, stream>>>(x, out, n4);
}

// Round 3
// 14.621 us; speedup vs baseline: 1.0721x; 1.0721x over previous
//
#include <hip/hip_runtime.h>

// out = -((1-x)-1), bit-exact collapse of the 2*T-step scan (see round 0).
// Nontemporal builtins need a native clang vector type, not HIP_vector_type.
typedef float f4 __attribute__((ext_vector_type(4)));

__global__ __launch_bounds__(256) void codec_kernel(const f4* __restrict__ x,
                                                    f4* __restrict__ out,
                                                    int n4) {
    int base = blockIdx.x * 512 + threadIdx.x;   // 2 f4 per thread

    if (base < n4) {
        f4 v = __builtin_nontemporal_load(&x[base]);
        f4 r;
        r.x = -((1.0f - v.x) - 1.0f);
        r.y = -((1.0f - v.y) - 1.0f);
        r.z = -((1.0f - v.z) - 1.0f);
        r.w = -((1.0f - v.w) - 1.0f);
        __builtin_nontemporal_store(r, &out[base]);
    }
    int j = base + 256;
    if (j < n4) {
        f4 v = __builtin_nontemporal_load(&x[j]);
        f4 r;
        r.x = -((1.0f - v.x) - 1.0f);
        r.y = -((1.0f - v.y) - 1.0f);
        r.z = -((1.0f - v.z) - 1.0f);
        r.w = -((1.0f - v.w) - 1.0f);
        __builtin_nontemporal_store(r, &out[j]);
    }
}

extern "C" void kernel_launch(void* const* d_in, const int* in_sizes, int n_in,
                              void* d_out, int out_size, void* d_ws, size_t ws_size,
                              hipStream_t stream) {
    const f4* x = (const f4*)d_in[0];
    f4* out = (f4*)d_out;
    int n = in_sizes[0];                 // 8388608
    int n4 = n / 4;                      // 2097152 f4
    int grid = (n4 + 511) / 512;         // 4096 blocks, 512 f4 each
    codec_kernel<<<grid, 256, 0, stream>>>(x, out, n4);
}